// Round 8
// baseline (225.217 us; speedup 1.0000x reference)
//
#include <hip/hip_runtime.h>
#include <math.h>

typedef _Float16 h8 __attribute__((ext_vector_type(8)));
typedef _Float16 h4 __attribute__((ext_vector_type(4)));
typedef float    f4 __attribute__((ext_vector_type(4)));

#define SAMPLES 64
#define HIDDEN  256

// Load one A-fragment's worth of fp32 weights: rows k0..k0+7 (guarded by
// KMAX), one column. For KMAX=256 the guard folds away; addresses become
// base + j*1024 immediate offsets (one addr calc + 8 global_load_dword).
template<int KMAX>
__device__ __forceinline__ void load_w8(const float* __restrict__ Wsrc,
                                        int col, int k0, float w[8])
{
#pragma unroll
    for (int j = 0; j < 8; ++j) {
        int k = k0 + j;
        w[j] = (KMAX == 256 || k < KMAX) ? Wsrc[k * 256 + col] : 0.0f;
    }
}

__device__ __forceinline__ void split8(const float w[8], h8& hi, h8& lo)
{
#pragma unroll
    for (int j = 0; j < 8; ++j) {
        _Float16 h = (_Float16)w[j];
        hi[j] = h;
        lo[j] = (_Float16)(w[j] - (float)h);
    }
}

__device__ __forceinline__ f4 mfma3(h8 ahi, h8 alo, h8 bhi, h8 blo, f4 c)
{
    c = __builtin_amdgcn_mfma_f32_16x16x32_f16(alo, bhi, c, 0, 0, 0);
    c = __builtin_amdgcn_mfma_f32_16x16x32_f16(ahi, blo, c, 0, 0, 0);
    c = __builtin_amdgcn_mfma_f32_16x16x32_f16(ahi, bhi, c, 0, 0, 0);
    return c;
}

// Swapped orientation: D[ch][samp] = W^T @ H^T. Wave wv owns channels
// wv*32..+31 (cht=0,1) x ALL 64 samples. Weights converted fp32->hi/lo f16
// on the fly; raw floats prefetched one kg ahead. 8 ds_read_b128/kg,
// 24 MFMA/kg per wave.
template<int NKG, int KMAX>
__device__ __forceinline__ void dense_layer(const float* __restrict__ Wsrc,
                                            const float*  __restrict__ bias,
                                            _Float16* Bhi, _Float16* Blo,
                                            int wv, int lane)
{
    const int q  = lane >> 4;
    const int jl = lane & 15;
    f4 acc[2][4];
#pragma unroll
    for (int cht = 0; cht < 2; ++cht) {
        f4 bb = ((const f4*)bias)[wv*8 + cht*4 + q];   // acc row r -> ch q*4+r
#pragma unroll
        for (int st = 0; st < 4; ++st) acc[cht][st] = bb;
    }
    const h8* bhp = (const h8*)Bhi;
    const h8* blp = (const h8*)Blo;

    const int k0b = (lane >> 4) << 3;          // 0,8,16,24
    const int col0 = wv*32 + (lane & 15);      // cht adds +16

    float wcur[2][8];
#pragma unroll
    for (int cht = 0; cht < 2; ++cht)
        load_w8<KMAX>(Wsrc, col0 + cht*16, k0b, wcur[cht]);      // kg=0

#pragma unroll
    for (int kg = 0; kg < NKG; ++kg) {
        h8 cah[2], cal[2];
#pragma unroll
        for (int cht = 0; cht < 2; ++cht)
            split8(wcur[cht], cah[cht], cal[cht]);

        float wnext[2][8];
        int kn = (kg + 1 < NKG) ? kg + 1 : kg;  // harmless re-load on last iter
#pragma unroll
        for (int cht = 0; cht < 2; ++cht)
            load_w8<KMAX>(Wsrc, col0 + cht*16, kn*32 + k0b, wnext[cht]);

        h8 bh[4], bl[4];
#pragma unroll
        for (int st = 0; st < 4; ++st) {
            int bi = (kg*4 + st)*64 + lane;     // ds_read_b128, conflict-free
            bh[st] = bhp[bi];
            bl[st] = blp[bi];
        }
#pragma unroll
        for (int cht = 0; cht < 2; ++cht)
#pragma unroll
            for (int st = 0; st < 4; ++st)
                acc[cht][st] = mfma3(cah[cht], cal[cht], bh[st], bl[st], acc[cht][st]);

#pragma unroll
        for (int cht = 0; cht < 2; ++cht)
#pragma unroll
            for (int j = 0; j < 8; ++j) wcur[cht][j] = wnext[cht][j];
    }

    __syncthreads();   // all waves done reading before in-place overwrite

    // relu + hi/lo split into next layer's B-frag layout: one ds_write_b64
    // per (cht,st) per array. ch = wv*32 + cht*16 + q*4 + r.
#pragma unroll
    for (int cht = 0; cht < 2; ++cht) {
        int lnp = jl + 16*(cht*2 + (q >> 1));
        int jb  = (q & 1)*4;
#pragma unroll
        for (int st = 0; st < 4; ++st) {
            h4 vh, vl;
#pragma unroll
            for (int r = 0; r < 4; ++r) {
                float v = fmaxf(acc[cht][st][r], 0.0f);
                _Float16 hh = (_Float16)v;
                vh[r] = hh;
                vl[r] = (_Float16)(v - (float)hh);
            }
            int base = ((wv*4 + st)*64 + lnp)*8 + jb;
            *(h4*)(Bhi + base) = vh;
            *(h4*)(Blo + base) = vl;
        }
    }
    __syncthreads();
}

// (512,2): 2nd arg = min BLOCKS/CU on hipcc (r4 evidence: (512,4) -> 64-VGPR
// cap -> scratch spill disaster). 128-VGPR cap matches the 64KB-LDS 2-block limit.
__launch_bounds__(512, 2)
__global__ void nerf_fused(const float* __restrict__ origins,
                           const float* __restrict__ dirs,
                           const float* __restrict__ nearp,
                           const float* __restrict__ farp,
                           const float* __restrict__ W0,
                           const float* __restrict__ b0,
                           const float* __restrict__ W1,
                           const float* __restrict__ b1,
                           const float* __restrict__ W2,
                           const float* __restrict__ b2,
                           const float* __restrict__ W3,
                           const float* __restrict__ b3,
                           float* __restrict__ out)
{
    extern __shared__ _Float16 sm[];
    _Float16* Bhi = sm;            // [kg][4st][64ln][8] = 16384 halfs = 32 KB
    _Float16* Blo = sm + 16384;    // 32 KB (total 64 KB -> 2 blocks/CU, 16 waves)

    const int tid  = threadIdx.x;
    const int wv   = tid >> 6;
    const int lane = tid & 63;
    const int ray  = blockIdx.x;

    const float near = nearp[0];
    const float far  = farp[0];
    const float step = (far - near) * (1.0f / 64.0f);

    const float ox = origins[ray*3+0], oy = origins[ray*3+1], oz = origins[ray*3+2];
    const float dx = dirs[ray*3+0],    dy = dirs[ray*3+1],    dz = dirs[ray*3+2];

    // ---- PE directly into B-frag layout (K padded 63->64): one h8 per thread
    {
        int b  = tid;                    // = (kg*4+st)*64 + ln
        int ln = b & 63;
        int sample = ((b >> 6) & 3)*16 + (ln & 15);
        int k0 = (b >> 8)*32 + ((ln >> 4) << 3);
        float mid = (near + (float)sample*step) + (near + (float)(sample+1)*step)*0.5f;
        float c3[3] = { ox + mid*dx, oy + mid*dy, oz + mid*dz };
        h8 vh, vl;
#pragma unroll
        for (int j = 0; j < 8; ++j) {
            int k = k0 + j;
            float v;
            if (k < 3) v = c3[k];
            else if (k < 63) {
                int t = k - 3, l = t/6, r = t%6, d = r%3;
                float a = c3[d] * (float)(1 << l);
                v = (r < 3) ? sinf(a) : cosf(a);
            } else v = 0.0f;
            _Float16 hh = (_Float16)v;
            vh[j] = hh;
            vl[j] = (_Float16)(v - (float)hh);
        }
        ((h8*)Bhi)[b] = vh;
        ((h8*)Blo)[b] = vl;
    }
    __syncthreads();

    dense_layer<2, 63>(W0, b0, Bhi, Blo, wv, lane);
    dense_layer<8, 256>(W1, b1, Bhi, Blo, wv, lane);
    dense_layer<8, 256>(W2, b2, Bhi, Blo, wv, lane);

    // ---- head: D[16pad ch][64 samp], K split across 8 waves (kg = wv)
    f4 hacc[4];
#pragma unroll
    for (int st = 0; st < 4; ++st) hacc[st] = (f4){0.f, 0.f, 0.f, 0.f};
    {
        const int col3 = lane & 15;
        float w3[8];
#pragma unroll
        for (int j = 0; j < 8; ++j) {
            int k = wv*32 + ((lane >> 4) << 3) + j;
            w3[j] = (col3 < 4) ? W3[k*4 + col3] : 0.0f;
        }
        h8 ah, al;
        split8(w3, ah, al);
        const h8* bhp = (const h8*)Bhi;
        const h8* blp = (const h8*)Blo;
#pragma unroll
        for (int st = 0; st < 4; ++st) {
            int bi = (wv*4 + st)*64 + lane;
            hacc[st] = mfma3(ah, al, bhp[bi], blp[bi], hacc[st]);
        }
    }
    __syncthreads();                       // B reads done -> safe to alias

    f4* part = (f4*)sm;                    // [wv][st][lane] f4 = 32 KB (Bhi region)
#pragma unroll
    for (int st = 0; st < 4; ++st) part[(wv*4 + st)*64 + lane] = hacc[st];
    __syncthreads();

    float* headv = (float*)(sm + 16384);   // [64 samp][4] f32 = 1 KB (Blo region)
    if (tid < 256) {
        int st = tid >> 6, l = tid & 63;
        f4 s = part[(0*4 + st)*64 + l];
#pragma unroll
        for (int w = 1; w < 8; ++w) s += part[(w*4 + st)*64 + l];
        int q = l >> 4, jl = l & 15;
        if (q == 0) {                      // rows 0..3 = the real 4 channels
            s += *(const f4*)b3;
            ((f4*)headv)[st*16 + jl] = s;  // [sample] -> (r,g,b,sigma)
        }
    }
    __syncthreads();

    // ---- compositing: wave 0, lane = sample
    if (tid < 64) {
        f4 f = ((const f4*)headv)[tid];
        const int p = tid;
        float sigma = fmaxf(f[3], 0.0f);
        float delta = (near + (float)(p + 1)*step) - (near + (float)p*step);
        float alpha = 1.0f - expf(-sigma * delta);
        float om    = 1.0f - alpha;

        float prod = om;
#pragma unroll
        for (int off = 1; off < 64; off <<= 1) {
            float v = __shfl_up(prod, off, 64);
            if (p >= off) prod *= v;
        }
        float T = __shfl_up(prod, 1, 64);
        if (p == 0) T = 1.0f;
        float w = T * alpha;

        float r  = w * (1.0f / (1.0f + expf(-f[0])));
        float g  = w * (1.0f / (1.0f + expf(-f[1])));
        float bb = w * (1.0f / (1.0f + expf(-f[2])));
#pragma unroll
        for (int off = 32; off > 0; off >>= 1) {
            r  += __shfl_down(r,  off, 64);
            g  += __shfl_down(g,  off, 64);
            bb += __shfl_down(bb, off, 64);
        }
        if (p == 0) {
            out[ray*3 + 0] = r;
            out[ray*3 + 1] = g;
            out[ray*3 + 2] = bb;
        }
    }
}

extern "C" void kernel_launch(void* const* d_in, const int* in_sizes, int n_in,
                              void* d_out, int out_size, void* d_ws, size_t ws_size,
                              hipStream_t stream) {
    const float* origins = (const float*)d_in[0];
    const float* dirs    = (const float*)d_in[1];
    const float* nearp   = (const float*)d_in[2];
    const float* farp    = (const float*)d_in[3];
    const float* W0      = (const float*)d_in[4];
    const float* b0      = (const float*)d_in[5];
    const float* W1      = (const float*)d_in[6];
    const float* b1      = (const float*)d_in[7];
    const float* W2      = (const float*)d_in[8];
    const float* b2      = (const float*)d_in[9];
    const float* W3      = (const float*)d_in[10];
    const float* b3      = (const float*)d_in[11];
    float* out           = (float*)d_out;

    const int nrays = in_sizes[0] / 3;

    const size_t shmem = 32768 * sizeof(_Float16);   // 64 KiB
    hipFuncSetAttribute(reinterpret_cast<const void*>(nerf_fused),
                        hipFuncAttributeMaxDynamicSharedMemorySize,
                        (int)shmem);
    nerf_fused<<<dim3(nrays), dim3(512), shmem, stream>>>(
        origins, dirs, nearp, farp,
        W0, b0, W1, b1, W2, b2, W3, b3, out);
}